// Round 1
// baseline (390.708 us; speedup 1.0000x reference)
//
#include <hip/hip_runtime.h>
#include <hip/hip_bf16.h>
#include <stdint.h>
#include <stddef.h>

typedef __attribute__((ext_vector_type(8))) short short8;
typedef __attribute__((ext_vector_type(4))) float floatx4;

#define AS_GLOBAL(p) (const __attribute__((address_space(1))) void*)(p)
#define AS_LDS(p)    (__attribute__((address_space(3))) void*)(p)

static constexpr int IN_DIM  = 4096;
static constexpr int OUT_DIM = 4096;
static constexpr int S_DIM   = 256;
static constexpr int S2      = 512;   // both branches concatenated along rank

// ---------------- prep: fold scales into sign weights ----------------

// W1[s,i] = v2[i] * sign(V[s,i])   (s<256: branch 1; s>=256: residual branch)
__global__ void build_w1_kernel(const float* __restrict__ V, const float* __restrict__ v2,
                                const float* __restrict__ V_R, const float* __restrict__ v2_R,
                                __hip_bfloat16* __restrict__ W1) {
  const int idx = blockIdx.x * 256 + threadIdx.x;   // over S2*IN_DIM
  const int i = idx & (IN_DIM - 1);
  const int s = idx >> 12;
  float w, sc;
  if (s < S_DIM) { w = V[s * IN_DIM + i];            sc = v2[i]; }
  else           { w = V_R[(s - S_DIM) * IN_DIM + i]; sc = v2_R[i]; }
  const float sg = (w > 0.f) ? 1.f : ((w < 0.f) ? -1.f : 0.f);
  W1[idx] = __float2bfloat16(sg * sc);
}

// W2[o,s] = u1[o]*v1[s]*u2[s] * sign(U[o,s])
__global__ void build_w2_kernel(const float* __restrict__ U, const float* __restrict__ u1,
                                const float* __restrict__ v1, const float* __restrict__ u2,
                                const float* __restrict__ U_R, const float* __restrict__ u1_R,
                                const float* __restrict__ v1_R, const float* __restrict__ u2_R,
                                __hip_bfloat16* __restrict__ W2) {
  const int idx = blockIdx.x * 256 + threadIdx.x;   // over OUT_DIM*S2
  const int s = idx & (S2 - 1);
  const int o = idx >> 9;
  float w, sc;
  if (s < S_DIM) { w = U[o * S_DIM + s];   sc = u1[o] * v1[s] * u2[s]; }
  else { const int ss = s - S_DIM; w = U_R[o * S_DIM + ss]; sc = u1_R[o] * v1_R[ss] * u2_R[ss]; }
  const float sg = (w > 0.f) ? 1.f : ((w < 0.f) ? -1.f : 0.f);
  W2[idx] = __float2bfloat16(sg * sc);
}

// ---------------- GEMM1: H[M,512] = bf16(x[M,4096]) @ W1[512,4096]^T ----------------
// A is fp32 in global; staged fp32 into LDS (XOR-swizzled 16B chunks to kill the
// stride-128B bank conflicts), converted to bf16 at fragment build.
__global__ __launch_bounds__(256, 2)
void gemm1_kernel(const float* __restrict__ A,
                  const __hip_bfloat16* __restrict__ B,
                  __hip_bfloat16* __restrict__ C) {
  constexpr int K = IN_DIM;   // 4096
  constexpr int N = S2;       // 512
  constexpr int BM = 64, BN = 128, BK = 32;

  __shared__ float As[BM * BK];             // swizzled 16B-chunk layout
  __shared__ __hip_bfloat16 Bs[BN * BK];    // [row][32] linear, 64B rows

  const int t = threadIdx.x;
  const int wave = t >> 6;
  const int lane = t & 63;
  const int r16 = lane & 15;
  const int quad = lane >> 4;

  // XCD swizzle: 512 blocks = 8 XCD * 64; the 4 N-tiles of one M-slab share an XCD.
  const int f = blockIdx.x;
  const int xcd = f & 7;
  const int l = f >> 3;
  const int tm0 = (xcd * 16 + (l & 15)) * BM;  // 128 M-tiles
  const int tn0 = (l >> 4) * BN;               // 4 N-tiles

  const int wm = (wave & 1) * 32;
  const int wn = (wave >> 1) * 64;

  floatx4 acc[2][4] = {};

  for (int k0 = 0; k0 < K; k0 += BK) {
    // stage A: 64 rows x 32 fp32 = 512 x 16B chunks, 2/thread, XOR-swizzled
#pragma unroll
    for (int i = 0; i < 2; ++i) {
      const int p = t + i * 256;
      const int row = p >> 3;
      const int ql = (p & 7) ^ (row & 7);
      const float* gp = A + (size_t)(tm0 + row) * K + k0 + ql * 4;
      __builtin_amdgcn_global_load_lds(AS_GLOBAL(gp), AS_LDS((char*)As + p * 16), 16, 0, 0);
    }
    // stage B: 128 rows x 32 bf16 = 512 x 16B chunks, 2/thread, linear
#pragma unroll
    for (int i = 0; i < 2; ++i) {
      const int p = t + i * 256;
      const int row = p >> 2;
      const int q = p & 3;
      const __hip_bfloat16* gp = B + (size_t)(tn0 + row) * K + k0 + q * 8;
      __builtin_amdgcn_global_load_lds(AS_GLOBAL(gp), AS_LDS((char*)Bs + p * 16), 16, 0, 0);
    }
    __syncthreads();

    short8 a[2];
    short8 b[4];
#pragma unroll
    for (int i = 0; i < 2; ++i) {
      const int ar = wm + i * 16 + r16;
      const int p0 = ar * 8 + ((quad * 2) ^ (ar & 7));
      const int p1 = ar * 8 + ((quad * 2 + 1) ^ (ar & 7));
      const floatx4 f0 = *reinterpret_cast<const floatx4*>((const char*)As + p0 * 16);
      const floatx4 f1 = *reinterpret_cast<const floatx4*>((const char*)As + p1 * 16);
      union { short8 v; __hip_bfloat16 h[8]; } u;
      u.h[0] = __float2bfloat16(f0.x); u.h[1] = __float2bfloat16(f0.y);
      u.h[2] = __float2bfloat16(f0.z); u.h[3] = __float2bfloat16(f0.w);
      u.h[4] = __float2bfloat16(f1.x); u.h[5] = __float2bfloat16(f1.y);
      u.h[6] = __float2bfloat16(f1.z); u.h[7] = __float2bfloat16(f1.w);
      a[i] = u.v;
    }
#pragma unroll
    for (int j = 0; j < 4; ++j) {
      const int br = wn + j * 16 + r16;
      b[j] = *reinterpret_cast<const short8*>((const char*)Bs + br * 64 + quad * 16);
    }
#pragma unroll
    for (int i = 0; i < 2; ++i)
#pragma unroll
      for (int j = 0; j < 4; ++j)
        acc[i][j] = __builtin_amdgcn_mfma_f32_16x16x32_bf16(a[i], b[j], acc[i][j], 0, 0, 0);
    __syncthreads();
  }

#pragma unroll
  for (int i = 0; i < 2; ++i)
#pragma unroll
    for (int j = 0; j < 4; ++j)
#pragma unroll
      for (int r = 0; r < 4; ++r) {
        const int row = tm0 + wm + i * 16 + quad * 4 + r;
        const int col = tn0 + wn + j * 16 + r16;
        C[(size_t)row * N + col] = __float2bfloat16(acc[i][j][r]);
      }
}

// ---------------- GEMM2: Y[M,4096] = H[M,512] @ W2[4096,512]^T + bias ----------------
__global__ __launch_bounds__(256, 2)
void gemm2_kernel(const __hip_bfloat16* __restrict__ A,
                  const __hip_bfloat16* __restrict__ B,
                  const float* __restrict__ bias,
                  float* __restrict__ C) {
  constexpr int K = S2;        // 512
  constexpr int N = OUT_DIM;   // 4096
  constexpr int BM = 128, BN = 128, BK = 32;

  __shared__ __hip_bfloat16 As[BM * BK];
  __shared__ __hip_bfloat16 Bs[BN * BK];

  const int t = threadIdx.x;
  const int wave = t >> 6;
  const int lane = t & 63;
  const int r16 = lane & 15;
  const int quad = lane >> 4;

  const int tm0 = blockIdx.y * BM;
  const int tn0 = blockIdx.x * BN;

  const int wm = (wave & 1) * 64;
  const int wn = (wave >> 1) * 64;

  floatx4 acc[4][4] = {};

  for (int k0 = 0; k0 < K; k0 += BK) {
#pragma unroll
    for (int i = 0; i < 2; ++i) {
      const int p = t + i * 256;
      const int row = p >> 2;
      const int q = p & 3;
      const __hip_bfloat16* gp = A + (size_t)(tm0 + row) * K + k0 + q * 8;
      __builtin_amdgcn_global_load_lds(AS_GLOBAL(gp), AS_LDS((char*)As + p * 16), 16, 0, 0);
    }
#pragma unroll
    for (int i = 0; i < 2; ++i) {
      const int p = t + i * 256;
      const int row = p >> 2;
      const int q = p & 3;
      const __hip_bfloat16* gp = B + (size_t)(tn0 + row) * K + k0 + q * 8;
      __builtin_amdgcn_global_load_lds(AS_GLOBAL(gp), AS_LDS((char*)Bs + p * 16), 16, 0, 0);
    }
    __syncthreads();

    short8 a[4], b[4];
#pragma unroll
    for (int i = 0; i < 4; ++i) {
      const int ar = wm + i * 16 + r16;
      a[i] = *reinterpret_cast<const short8*>((const char*)As + ar * 64 + quad * 16);
    }
#pragma unroll
    for (int j = 0; j < 4; ++j) {
      const int br = wn + j * 16 + r16;
      b[j] = *reinterpret_cast<const short8*>((const char*)Bs + br * 64 + quad * 16);
    }
#pragma unroll
    for (int i = 0; i < 4; ++i)
#pragma unroll
      for (int j = 0; j < 4; ++j)
        acc[i][j] = __builtin_amdgcn_mfma_f32_16x16x32_bf16(a[i], b[j], acc[i][j], 0, 0, 0);
    __syncthreads();
  }

#pragma unroll
  for (int i = 0; i < 4; ++i)
#pragma unroll
    for (int j = 0; j < 4; ++j)
#pragma unroll
      for (int r = 0; r < 4; ++r) {
        const int row = tm0 + wm + i * 16 + quad * 4 + r;
        const int col = tn0 + wn + j * 16 + r16;
        C[(size_t)row * N + col] = acc[i][j][r] + bias[col];
      }
}

// ---------------- launch ----------------
extern "C" void kernel_launch(void* const* d_in, const int* in_sizes, int n_in,
                              void* d_out, int out_size, void* d_ws, size_t ws_size,
                              hipStream_t stream) {
  const float* x    = (const float*)d_in[0];
  const float* V    = (const float*)d_in[1];
  const float* U    = (const float*)d_in[2];
  const float* v1   = (const float*)d_in[3];
  const float* v2   = (const float*)d_in[4];
  const float* u1   = (const float*)d_in[5];
  const float* u2   = (const float*)d_in[6];
  const float* V_R  = (const float*)d_in[7];
  const float* U_R  = (const float*)d_in[8];
  const float* v1_R = (const float*)d_in[9];
  const float* v2_R = (const float*)d_in[10];
  const float* u1_R = (const float*)d_in[11];
  const float* u2_R = (const float*)d_in[12];
  const float* bias = (const float*)d_in[13];
  float* out = (float*)d_out;

  const int M = in_sizes[0] / IN_DIM;   // 8192

  char* ws = (char*)d_ws;
  __hip_bfloat16* W1 = (__hip_bfloat16*)ws;                                  // 512*4096 bf16 = 4MB
  __hip_bfloat16* W2 = (__hip_bfloat16*)(ws + (size_t)S2 * IN_DIM * 2);      // 4096*512 bf16 = 4MB
  __hip_bfloat16* H  = (__hip_bfloat16*)(ws + (size_t)S2 * IN_DIM * 4);      // M*512 bf16 = 8MB

  build_w1_kernel<<<(S2 * IN_DIM) / 256, 256, 0, stream>>>(V, v2, V_R, v2_R, W1);
  build_w2_kernel<<<(OUT_DIM * S2) / 256, 256, 0, stream>>>(U, u1, v1, u2, U_R, u1_R, v1_R, u2_R, W2);

  // GEMM1: 128 M-tiles (BM=64) x 4 N-tiles (BN=128) = 512 blocks, XCD-swizzled in-kernel
  gemm1_kernel<<<(M / 64) * (S2 / 128), 256, 0, stream>>>(x, W1, H);

  // GEMM2: 64 x 32 = 2048 blocks
  gemm2_kernel<<<dim3(OUT_DIM / 128, M / 128), 256, 0, stream>>>(H, W2, bias, out);
}

// Round 2
// 351.112 us; speedup vs baseline: 1.1128x; 1.1128x over previous
//
#include <hip/hip_runtime.h>
#include <hip/hip_bf16.h>
#include <stdint.h>
#include <stddef.h>

typedef __attribute__((ext_vector_type(8))) short short8;
typedef __attribute__((ext_vector_type(4))) float floatx4;

#define AS_GLOBAL(p) (const __attribute__((address_space(1))) void*)(p)
#define AS_LDS(p)    (__attribute__((address_space(3))) void*)(p)

static constexpr int IN_DIM  = 4096;
static constexpr int OUT_DIM = 4096;
static constexpr int S_DIM   = 256;
static constexpr int S2      = 512;   // both branches concatenated along rank

// ---------------- prep: fold scales into sign weights ----------------

// W1[s,i] = v2[i] * sign(V[s,i])   (s<256: branch 1; s>=256: residual branch)
__global__ void build_w1_kernel(const float* __restrict__ V, const float* __restrict__ v2,
                                const float* __restrict__ V_R, const float* __restrict__ v2_R,
                                __hip_bfloat16* __restrict__ W1) {
  const int idx4 = (blockIdx.x * 256 + threadIdx.x) * 4;   // over S2*IN_DIM
  const int i = idx4 & (IN_DIM - 1);
  const int s = idx4 >> 12;
  floatx4 w, sc;
  if (s < S_DIM) {
    w  = *(const floatx4*)(V + s * IN_DIM + i);
    sc = *(const floatx4*)(v2 + i);
  } else {
    w  = *(const floatx4*)(V_R + (s - S_DIM) * IN_DIM + i);
    sc = *(const floatx4*)(v2_R + i);
  }
  union { ushort4 v; __hip_bfloat16 h[4]; } u;
#pragma unroll
  for (int j = 0; j < 4; ++j) {
    const float sg = (w[j] > 0.f) ? 1.f : ((w[j] < 0.f) ? -1.f : 0.f);
    u.h[j] = __float2bfloat16(sg * sc[j]);
  }
  *(ushort4*)((unsigned short*)W1 + idx4) = u.v;
}

// W2[o,s] = u1[o]*v1[s]*u2[s] * sign(U[o,s])
__global__ void build_w2_kernel(const float* __restrict__ U, const float* __restrict__ u1,
                                const float* __restrict__ v1, const float* __restrict__ u2,
                                const float* __restrict__ U_R, const float* __restrict__ u1_R,
                                const float* __restrict__ v1_R, const float* __restrict__ u2_R,
                                __hip_bfloat16* __restrict__ W2) {
  const int idx4 = (blockIdx.x * 256 + threadIdx.x) * 4;   // over OUT_DIM*S2
  const int s = idx4 & (S2 - 1);
  const int o = idx4 >> 9;
  floatx4 w, scs;
  float sco;
  if (s < S_DIM) {
    w   = *(const floatx4*)(U + o * S_DIM + s);
    sco = u1[o];
    const floatx4 a = *(const floatx4*)(v1 + s);
    const floatx4 b = *(const floatx4*)(u2 + s);
    scs = a * b;
  } else {
    const int ss = s - S_DIM;
    w   = *(const floatx4*)(U_R + o * S_DIM + ss);
    sco = u1_R[o];
    const floatx4 a = *(const floatx4*)(v1_R + ss);
    const floatx4 b = *(const floatx4*)(u2_R + ss);
    scs = a * b;
  }
  union { ushort4 v; __hip_bfloat16 h[4]; } u;
#pragma unroll
  for (int j = 0; j < 4; ++j) {
    const float sg = (w[j] > 0.f) ? 1.f : ((w[j] < 0.f) ? -1.f : 0.f);
    u.h[j] = __float2bfloat16(sg * sco * scs[j]);
  }
  *(ushort4*)((unsigned short*)W2 + idx4) = u.v;
}

// ---------------- cvt: x fp32 -> bf16 ----------------
__global__ void cvt_x_kernel(const float* __restrict__ x, __hip_bfloat16* __restrict__ xb) {
  const int idx = blockIdx.x * 256 + threadIdx.x;   // 8 elems / thread
  const floatx4 f0 = *((const floatx4*)x + idx * 2);
  const floatx4 f1 = *((const floatx4*)x + idx * 2 + 1);
  union { short8 v; __hip_bfloat16 h[8]; } u;
  u.h[0] = __float2bfloat16(f0.x); u.h[1] = __float2bfloat16(f0.y);
  u.h[2] = __float2bfloat16(f0.z); u.h[3] = __float2bfloat16(f0.w);
  u.h[4] = __float2bfloat16(f1.x); u.h[5] = __float2bfloat16(f1.y);
  u.h[6] = __float2bfloat16(f1.z); u.h[7] = __float2bfloat16(f1.w);
  *((short8*)xb + idx) = u.v;
}

// ---------------- GEMM1: H[M,512] = Xb[M,4096] @ W1[512,4096]^T ----------------
// BM=128, BN=64, BK=64. XOR-swizzled LDS chunk layout (chunk = 16B):
//   LDS chunk index for logical (row, kc) is row*8 + (kc ^ (row&7)).
// Staging keeps global_load_lds's lane-contiguous LDS constraint by permuting
// WHICH global chunk each lane fetches instead of where it stores.
__global__ __launch_bounds__(256, 2)
void gemm1_kernel(const __hip_bfloat16* __restrict__ A,
                  const __hip_bfloat16* __restrict__ B,
                  __hip_bfloat16* __restrict__ C) {
  constexpr int K = IN_DIM;   // 4096
  constexpr int N = S2;       // 512
  constexpr int BM = 128, BN = 64, BK = 64;

  __shared__ __hip_bfloat16 As[BM * BK];   // 16 KB
  __shared__ __hip_bfloat16 Bs[BN * BK];   // 8 KB

  const int t = threadIdx.x;
  const int wave = t >> 6;
  const int lane = t & 63;
  const int r16 = lane & 15;
  const int quad = lane >> 4;

  // XCD swizzle: 512 blocks; XCD c handles M-tiles [c*8, c*8+8) x all 8 N-tiles.
  // W1 (4MB) stays resident in that XCD's L2; each x M-slab read once per XCD.
  const int f = blockIdx.x;
  const int c = f & 7;
  const int l = f >> 3;              // [0,64)
  const int tm0 = (c * 8 + (l >> 3)) * BM;
  const int tn0 = (l & 7) * BN;

  const int wm = (wave & 1) * 64;
  const int wn = (wave >> 1) * 32;

  floatx4 acc[4][2] = {};

  for (int k0 = 0; k0 < K; k0 += BK) {
    // stage A: 1024 chunks (16B), 4/thread
#pragma unroll
    for (int i = 0; i < 4; ++i) {
      const int p = t + i * 256;
      const int row = p >> 3;
      const int ql = (p & 7) ^ (row & 7);
      const __hip_bfloat16* gp = A + (size_t)(tm0 + row) * K + k0 + ql * 8;
      __builtin_amdgcn_global_load_lds(AS_GLOBAL(gp), AS_LDS((char*)As + p * 16), 16, 0, 0);
    }
    // stage B: 512 chunks, 2/thread
#pragma unroll
    for (int i = 0; i < 2; ++i) {
      const int p = t + i * 256;
      const int row = p >> 3;
      const int ql = (p & 7) ^ (row & 7);
      const __hip_bfloat16* gp = B + (size_t)(tn0 + row) * K + k0 + ql * 8;
      __builtin_amdgcn_global_load_lds(AS_GLOBAL(gp), AS_LDS((char*)Bs + p * 16), 16, 0, 0);
    }
    __syncthreads();

#pragma unroll
    for (int ks = 0; ks < 2; ++ks) {
      short8 a[4], b[2];
      const int cc = ks * 4 + quad;
#pragma unroll
      for (int i = 0; i < 4; ++i) {
        const int ar = wm + i * 16 + r16;
        a[i] = *reinterpret_cast<const short8*>((const char*)As + (ar * 8 + (cc ^ (ar & 7))) * 16);
      }
#pragma unroll
      for (int j = 0; j < 2; ++j) {
        const int br = wn + j * 16 + r16;
        b[j] = *reinterpret_cast<const short8*>((const char*)Bs + (br * 8 + (cc ^ (br & 7))) * 16);
      }
#pragma unroll
      for (int i = 0; i < 4; ++i)
#pragma unroll
        for (int j = 0; j < 2; ++j)
          acc[i][j] = __builtin_amdgcn_mfma_f32_16x16x32_bf16(a[i], b[j], acc[i][j], 0, 0, 0);
    }
    __syncthreads();
  }

#pragma unroll
  for (int i = 0; i < 4; ++i)
#pragma unroll
    for (int j = 0; j < 2; ++j)
#pragma unroll
      for (int r = 0; r < 4; ++r) {
        const int row = tm0 + wm + i * 16 + quad * 4 + r;
        const int col = tn0 + wn + j * 16 + r16;
        C[(size_t)row * N + col] = __float2bfloat16(acc[i][j][r]);
      }
}

// ---------------- GEMM2: Y[M,4096] = H[M,512] @ W2[4096,512]^T + bias ----------------
// BM=128, BN=128, BK=64 -> only 8 K-iterations, 32 MFMA/wave per barrier.
__global__ __launch_bounds__(256, 2)
void gemm2_kernel(const __hip_bfloat16* __restrict__ A,
                  const __hip_bfloat16* __restrict__ B,
                  const float* __restrict__ bias,
                  float* __restrict__ C) {
  constexpr int K = S2;        // 512
  constexpr int N = OUT_DIM;   // 4096
  constexpr int BM = 128, BN = 128, BK = 64;

  __shared__ __hip_bfloat16 As[BM * BK];   // 16 KB
  __shared__ __hip_bfloat16 Bs[BN * BK];   // 16 KB

  const int t = threadIdx.x;
  const int wave = t >> 6;
  const int lane = t & 63;
  const int r16 = lane & 15;
  const int quad = lane >> 4;

  // XCD swizzle: 2048 blocks; XCD c handles M-tiles [c*8,c*8+8) x all 32 N-tiles.
  const int f = blockIdx.x;
  const int c = f & 7;
  const int l = f >> 3;              // [0,256)
  const int tm0 = (c * 8 + (l >> 5)) * BM;
  const int tn0 = (l & 31) * BN;

  const int wm = (wave & 1) * 64;
  const int wn = (wave >> 1) * 64;

  floatx4 acc[4][4] = {};

  for (int k0 = 0; k0 < K; k0 += BK) {
#pragma unroll
    for (int i = 0; i < 4; ++i) {
      const int p = t + i * 256;
      const int row = p >> 3;
      const int ql = (p & 7) ^ (row & 7);
      const __hip_bfloat16* gp = A + (size_t)(tm0 + row) * K + k0 + ql * 8;
      __builtin_amdgcn_global_load_lds(AS_GLOBAL(gp), AS_LDS((char*)As + p * 16), 16, 0, 0);
    }
#pragma unroll
    for (int i = 0; i < 4; ++i) {
      const int p = t + i * 256;
      const int row = p >> 3;
      const int ql = (p & 7) ^ (row & 7);
      const __hip_bfloat16* gp = B + (size_t)(tn0 + row) * K + k0 + ql * 8;
      __builtin_amdgcn_global_load_lds(AS_GLOBAL(gp), AS_LDS((char*)Bs + p * 16), 16, 0, 0);
    }
    __syncthreads();

#pragma unroll
    for (int ks = 0; ks < 2; ++ks) {
      short8 a[4], b[4];
      const int cc = ks * 4 + quad;
#pragma unroll
      for (int i = 0; i < 4; ++i) {
        const int ar = wm + i * 16 + r16;
        a[i] = *reinterpret_cast<const short8*>((const char*)As + (ar * 8 + (cc ^ (ar & 7))) * 16);
      }
#pragma unroll
      for (int j = 0; j < 4; ++j) {
        const int br = wn + j * 16 + r16;
        b[j] = *reinterpret_cast<const short8*>((const char*)Bs + (br * 8 + (cc ^ (br & 7))) * 16);
      }
#pragma unroll
      for (int i = 0; i < 4; ++i)
#pragma unroll
        for (int j = 0; j < 4; ++j)
          acc[i][j] = __builtin_amdgcn_mfma_f32_16x16x32_bf16(a[i], b[j], acc[i][j], 0, 0, 0);
    }
    __syncthreads();
  }

  // epilogue: bias + fp32 store
  float bi[4];
#pragma unroll
  for (int j = 0; j < 4; ++j) bi[j] = bias[tn0 + wn + j * 16 + r16];

#pragma unroll
  for (int i = 0; i < 4; ++i)
#pragma unroll
    for (int j = 0; j < 4; ++j)
#pragma unroll
      for (int r = 0; r < 4; ++r) {
        const int row = tm0 + wm + i * 16 + quad * 4 + r;
        const int col = tn0 + wn + j * 16 + r16;
        C[(size_t)row * N + col] = acc[i][j][r] + bi[j];
      }
}

// ---------------- launch ----------------
extern "C" void kernel_launch(void* const* d_in, const int* in_sizes, int n_in,
                              void* d_out, int out_size, void* d_ws, size_t ws_size,
                              hipStream_t stream) {
  const float* x    = (const float*)d_in[0];
  const float* V    = (const float*)d_in[1];
  const float* U    = (const float*)d_in[2];
  const float* v1   = (const float*)d_in[3];
  const float* v2   = (const float*)d_in[4];
  const float* u1   = (const float*)d_in[5];
  const float* u2   = (const float*)d_in[6];
  const float* V_R  = (const float*)d_in[7];
  const float* U_R  = (const float*)d_in[8];
  const float* v1_R = (const float*)d_in[9];
  const float* v2_R = (const float*)d_in[10];
  const float* u1_R = (const float*)d_in[11];
  const float* u2_R = (const float*)d_in[12];
  const float* bias = (const float*)d_in[13];
  float* out = (float*)d_out;

  const int M = in_sizes[0] / IN_DIM;   // 8192

  char* ws = (char*)d_ws;
  __hip_bfloat16* W1 = (__hip_bfloat16*)ws;                                   // 4 MB
  __hip_bfloat16* W2 = (__hip_bfloat16*)(ws + (size_t)4 * 1024 * 1024);       // 4 MB
  __hip_bfloat16* H  = (__hip_bfloat16*)(ws + (size_t)8 * 1024 * 1024);       // M*512*2 = 8 MB
  __hip_bfloat16* Xb = (__hip_bfloat16*)(ws + (size_t)16 * 1024 * 1024);      // M*4096*2 = 64 MB

  build_w1_kernel<<<(S2 * IN_DIM) / 1024, 256, 0, stream>>>(V, v2, V_R, v2_R, W1);
  build_w2_kernel<<<(OUT_DIM * S2) / 1024, 256, 0, stream>>>(U, u1, v1, u2, U_R, u1_R, v1_R, u2_R, W2);
  cvt_x_kernel<<<(M * IN_DIM) / (8 * 256), 256, 0, stream>>>(x, Xb);

  // GEMM1: (M/128) x (512/64) = 64 x 8 = 512 blocks, XCD-swizzled in-kernel
  gemm1_kernel<<<(M / 128) * (S2 / 64), 256, 0, stream>>>(Xb, W1, H);

  // GEMM2: (M/128) x (4096/128) = 64 x 32 = 2048 blocks
  gemm2_kernel<<<(M / 128) * (OUT_DIM / 128), 256, 0, stream>>>(H, W2, bias, out);
}

// Round 3
// 345.431 us; speedup vs baseline: 1.1311x; 1.0164x over previous
//
#include <hip/hip_runtime.h>
#include <hip/hip_bf16.h>
#include <stdint.h>
#include <stddef.h>

typedef __attribute__((ext_vector_type(8))) short short8;
typedef __attribute__((ext_vector_type(4))) float floatx4;

#define AS_GLOBAL(p) (const __attribute__((address_space(1))) void*)(p)
#define AS_LDS(p)    (__attribute__((address_space(3))) void*)(p)

static constexpr int IN_DIM  = 4096;
static constexpr int OUT_DIM = 4096;
static constexpr int S_DIM   = 256;
static constexpr int S2      = 512;   // both branches concatenated along rank

// ---------------- fused prep: W1, W2, x->bf16 in ONE launch ----------------
// blocks [0, 2048):          W1[s,i] = v2[i] * sign(V[s,i])          (4 elem/thread)
// blocks [2048, 4096):       W2[o,s] = u1[o]*v1[s]*u2[s]*sign(U[o,s]) (4 elem/thread)
// blocks [4096, 20480):      Xb = bf16(x)                             (8 elem/thread)
__global__ void prep_kernel(const float* __restrict__ V, const float* __restrict__ v2,
                            const float* __restrict__ V_R, const float* __restrict__ v2_R,
                            const float* __restrict__ U, const float* __restrict__ u1,
                            const float* __restrict__ v1, const float* __restrict__ u2,
                            const float* __restrict__ U_R, const float* __restrict__ u1_R,
                            const float* __restrict__ v1_R, const float* __restrict__ u2_R,
                            const float* __restrict__ x,
                            __hip_bfloat16* __restrict__ W1,
                            __hip_bfloat16* __restrict__ W2,
                            __hip_bfloat16* __restrict__ Xb) {
  const int bid = blockIdx.x;
  if (bid < 2048) {
    const int idx4 = (bid * 256 + threadIdx.x) * 4;   // over S2*IN_DIM
    const int i = idx4 & (IN_DIM - 1);
    const int s = idx4 >> 12;
    floatx4 w, sc;
    if (s < S_DIM) {
      w  = *(const floatx4*)(V + s * IN_DIM + i);
      sc = *(const floatx4*)(v2 + i);
    } else {
      w  = *(const floatx4*)(V_R + (s - S_DIM) * IN_DIM + i);
      sc = *(const floatx4*)(v2_R + i);
    }
    union { ushort4 v; __hip_bfloat16 h[4]; } u;
#pragma unroll
    for (int j = 0; j < 4; ++j) {
      const float sg = (w[j] > 0.f) ? 1.f : ((w[j] < 0.f) ? -1.f : 0.f);
      u.h[j] = __float2bfloat16(sg * sc[j]);
    }
    *(ushort4*)((unsigned short*)W1 + idx4) = u.v;
  } else if (bid < 4096) {
    const int idx4 = ((bid - 2048) * 256 + threadIdx.x) * 4;   // over OUT_DIM*S2
    const int s = idx4 & (S2 - 1);
    const int o = idx4 >> 9;
    floatx4 w, scs;
    float sco;
    if (s < S_DIM) {
      w   = *(const floatx4*)(U + o * S_DIM + s);
      sco = u1[o];
      const floatx4 a = *(const floatx4*)(v1 + s);
      const floatx4 b = *(const floatx4*)(u2 + s);
      scs = a * b;
    } else {
      const int ss = s - S_DIM;
      w   = *(const floatx4*)(U_R + o * S_DIM + ss);
      sco = u1_R[o];
      const floatx4 a = *(const floatx4*)(v1_R + ss);
      const floatx4 b = *(const floatx4*)(u2_R + ss);
      scs = a * b;
    }
    union { ushort4 v; __hip_bfloat16 h[4]; } u;
#pragma unroll
    for (int j = 0; j < 4; ++j) {
      const float sg = (w[j] > 0.f) ? 1.f : ((w[j] < 0.f) ? -1.f : 0.f);
      u.h[j] = __float2bfloat16(sg * sco * scs[j]);
    }
    *(ushort4*)((unsigned short*)W2 + idx4) = u.v;
  } else {
    const int idx = (bid - 4096) * 256 + threadIdx.x;   // 8 floats / thread
    const floatx4 f0 = *((const floatx4*)x + idx * 2);
    const floatx4 f1 = *((const floatx4*)x + idx * 2 + 1);
    union { short8 v; __hip_bfloat16 h[8]; } u;
    u.h[0] = __float2bfloat16(f0.x); u.h[1] = __float2bfloat16(f0.y);
    u.h[2] = __float2bfloat16(f0.z); u.h[3] = __float2bfloat16(f0.w);
    u.h[4] = __float2bfloat16(f1.x); u.h[5] = __float2bfloat16(f1.y);
    u.h[6] = __float2bfloat16(f1.z); u.h[7] = __float2bfloat16(f1.w);
    *((short8*)Xb + idx) = u.v;
  }
}

// ---------------- GEMM1: H[M,512] = Xb[M,4096] @ W1[512,4096]^T ----------------
// BM=128, BN=64, BK=64, DOUBLE-BUFFERED LDS: loads for tile k+1 are in flight
// across the whole MFMA phase of tile k (grid gives only 2 blocks/CU, so
// implicit cross-block overlap alone can't hide the vmcnt(0) barrier drain).
// XOR-swizzled 16B-chunk layout: chunk(row,kc) at index row*8 + (kc ^ (row&7)).
__global__ __launch_bounds__(256, 2)
void gemm1_kernel(const __hip_bfloat16* __restrict__ A,
                  const __hip_bfloat16* __restrict__ B,
                  __hip_bfloat16* __restrict__ C) {
  constexpr int K = IN_DIM;   // 4096
  constexpr int N = S2;       // 512
  constexpr int BM = 128, BN = 64, BK = 64;

  __shared__ __hip_bfloat16 As[2][BM * BK];   // 2 x 16 KB
  __shared__ __hip_bfloat16 Bs[2][BN * BK];   // 2 x 8 KB

  const int t = threadIdx.x;
  const int wave = t >> 6;
  const int lane = t & 63;
  const int r16 = lane & 15;
  const int quad = lane >> 4;

  // XCD swizzle: 512 blocks; XCD c handles M-tiles [c*8, c*8+8) x all 8 N-tiles.
  const int f = blockIdx.x;
  const int c = f & 7;
  const int l = f >> 3;              // [0,64)
  const int tm0 = (c * 8 + (l >> 3)) * BM;
  const int tn0 = (l & 7) * BN;

  const int wm = (wave & 1) * 64;
  const int wn = (wave >> 1) * 32;

  floatx4 acc[4][2] = {};

  // staging assignments (computed once)
  const int pa_row = t >> 3;                       // A: 4 chunks/thread, base p = t
  const int pa_ql0 = (t & 7);
  const int pb_row = t >> 3;

  auto stage = [&](int buf, int k0) {
#pragma unroll
    for (int i = 0; i < 4; ++i) {
      const int p = t + i * 256;
      const int row = p >> 3;
      const int ql = (p & 7) ^ (row & 7);
      const __hip_bfloat16* gp = A + (size_t)(tm0 + row) * K + k0 + ql * 8;
      __builtin_amdgcn_global_load_lds(AS_GLOBAL(gp), AS_LDS((char*)&As[buf][0] + p * 16), 16, 0, 0);
    }
#pragma unroll
    for (int i = 0; i < 2; ++i) {
      const int p = t + i * 256;
      const int row = p >> 3;
      const int ql = (p & 7) ^ (row & 7);
      const __hip_bfloat16* gp = B + (size_t)(tn0 + row) * K + k0 + ql * 8;
      __builtin_amdgcn_global_load_lds(AS_GLOBAL(gp), AS_LDS((char*)&Bs[buf][0] + p * 16), 16, 0, 0);
    }
  };

  stage(0, 0);
  __syncthreads();   // one-time prologue drain

  int buf = 0;
  for (int k0 = 0; k0 < K; k0 += BK) {
    if (k0 + BK < K) stage(buf ^ 1, k0 + BK);   // in flight during MFMA phase

    const char* as = (const char*)&As[buf][0];
    const char* bs = (const char*)&Bs[buf][0];
#pragma unroll
    for (int ks = 0; ks < 2; ++ks) {
      short8 a[4], b[2];
      const int cc = ks * 4 + quad;
#pragma unroll
      for (int i = 0; i < 4; ++i) {
        const int ar = wm + i * 16 + r16;
        a[i] = *reinterpret_cast<const short8*>(as + (ar * 8 + (cc ^ (ar & 7))) * 16);
      }
#pragma unroll
      for (int j = 0; j < 2; ++j) {
        const int br = wn + j * 16 + r16;
        b[j] = *reinterpret_cast<const short8*>(bs + (br * 8 + (cc ^ (br & 7))) * 16);
      }
#pragma unroll
      for (int i = 0; i < 4; ++i)
#pragma unroll
        for (int j = 0; j < 2; ++j)
          acc[i][j] = __builtin_amdgcn_mfma_f32_16x16x32_bf16(a[i], b[j], acc[i][j], 0, 0, 0);
    }
    __syncthreads();   // drains next-tile loads (overlapped) + protects buf reuse
    buf ^= 1;
  }

#pragma unroll
  for (int i = 0; i < 4; ++i)
#pragma unroll
    for (int j = 0; j < 2; ++j)
#pragma unroll
      for (int r = 0; r < 4; ++r) {
        const int row = tm0 + wm + i * 16 + quad * 4 + r;
        const int col = tn0 + wn + j * 16 + r16;
        C[(size_t)row * N + col] = __float2bfloat16(acc[i][j][r]);
      }
}

// ---------------- GEMM2: Y[M,4096] = H[M,512] @ W2[4096,512]^T + bias ----------------
// BM=128, BN=128, BK=64 -> 8 K-iterations, 32 MFMA/wave per barrier.
// launch_bounds(256,3): 3 blocks/CU (LDS 32KB*3=96KB, VGPR<=170) for overlap.
__global__ __launch_bounds__(256, 3)
void gemm2_kernel(const __hip_bfloat16* __restrict__ A,
                  const __hip_bfloat16* __restrict__ B,
                  const float* __restrict__ bias,
                  float* __restrict__ C) {
  constexpr int K = S2;        // 512
  constexpr int N = OUT_DIM;   // 4096
  constexpr int BM = 128, BN = 128, BK = 64;

  __shared__ __hip_bfloat16 As[BM * BK];   // 16 KB
  __shared__ __hip_bfloat16 Bs[BN * BK];   // 16 KB

  const int t = threadIdx.x;
  const int wave = t >> 6;
  const int lane = t & 63;
  const int r16 = lane & 15;
  const int quad = lane >> 4;

  // XCD swizzle: 2048 blocks; XCD c handles M-tiles [c*8,c*8+8) x all 32 N-tiles.
  const int f = blockIdx.x;
  const int c = f & 7;
  const int l = f >> 3;              // [0,256)
  const int tm0 = (c * 8 + (l >> 5)) * BM;
  const int tn0 = (l & 31) * BN;

  const int wm = (wave & 1) * 64;
  const int wn = (wave >> 1) * 64;

  floatx4 acc[4][4] = {};

  for (int k0 = 0; k0 < K; k0 += BK) {
#pragma unroll
    for (int i = 0; i < 4; ++i) {
      const int p = t + i * 256;
      const int row = p >> 3;
      const int ql = (p & 7) ^ (row & 7);
      const __hip_bfloat16* gp = A + (size_t)(tm0 + row) * K + k0 + ql * 8;
      __builtin_amdgcn_global_load_lds(AS_GLOBAL(gp), AS_LDS((char*)As + p * 16), 16, 0, 0);
    }
#pragma unroll
    for (int i = 0; i < 4; ++i) {
      const int p = t + i * 256;
      const int row = p >> 3;
      const int ql = (p & 7) ^ (row & 7);
      const __hip_bfloat16* gp = B + (size_t)(tn0 + row) * K + k0 + ql * 8;
      __builtin_amdgcn_global_load_lds(AS_GLOBAL(gp), AS_LDS((char*)Bs + p * 16), 16, 0, 0);
    }
    __syncthreads();

#pragma unroll
    for (int ks = 0; ks < 2; ++ks) {
      short8 a[4], b[4];
      const int cc = ks * 4 + quad;
#pragma unroll
      for (int i = 0; i < 4; ++i) {
        const int ar = wm + i * 16 + r16;
        a[i] = *reinterpret_cast<const short8*>((const char*)As + (ar * 8 + (cc ^ (ar & 7))) * 16);
      }
#pragma unroll
      for (int j = 0; j < 4; ++j) {
        const int br = wn + j * 16 + r16;
        b[j] = *reinterpret_cast<const short8*>((const char*)Bs + (br * 8 + (cc ^ (br & 7))) * 16);
      }
#pragma unroll
      for (int i = 0; i < 4; ++i)
#pragma unroll
        for (int j = 0; j < 4; ++j)
          acc[i][j] = __builtin_amdgcn_mfma_f32_16x16x32_bf16(a[i], b[j], acc[i][j], 0, 0, 0);
    }
    __syncthreads();
  }

  // epilogue: bias + fp32 store
  float bi[4];
#pragma unroll
  for (int j = 0; j < 4; ++j) bi[j] = bias[tn0 + wn + j * 16 + r16];

#pragma unroll
  for (int i = 0; i < 4; ++i)
#pragma unroll
    for (int j = 0; j < 4; ++j)
#pragma unroll
      for (int r = 0; r < 4; ++r) {
        const int row = tm0 + wm + i * 16 + quad * 4 + r;
        const int col = tn0 + wn + j * 16 + r16;
        C[(size_t)row * N + col] = acc[i][j][r] + bi[j];
      }
}

// ---------------- launch ----------------
extern "C" void kernel_launch(void* const* d_in, const int* in_sizes, int n_in,
                              void* d_out, int out_size, void* d_ws, size_t ws_size,
                              hipStream_t stream) {
  const float* x    = (const float*)d_in[0];
  const float* V    = (const float*)d_in[1];
  const float* U    = (const float*)d_in[2];
  const float* v1   = (const float*)d_in[3];
  const float* v2   = (const float*)d_in[4];
  const float* u1   = (const float*)d_in[5];
  const float* u2   = (const float*)d_in[6];
  const float* V_R  = (const float*)d_in[7];
  const float* U_R  = (const float*)d_in[8];
  const float* v1_R = (const float*)d_in[9];
  const float* v2_R = (const float*)d_in[10];
  const float* u1_R = (const float*)d_in[11];
  const float* u2_R = (const float*)d_in[12];
  const float* bias = (const float*)d_in[13];
  float* out = (float*)d_out;

  const int M = in_sizes[0] / IN_DIM;   // 8192

  char* ws = (char*)d_ws;
  __hip_bfloat16* W1 = (__hip_bfloat16*)ws;                                   // 4 MB
  __hip_bfloat16* W2 = (__hip_bfloat16*)(ws + (size_t)4 * 1024 * 1024);       // 4 MB
  __hip_bfloat16* H  = (__hip_bfloat16*)(ws + (size_t)8 * 1024 * 1024);       // M*512*2 = 8 MB
  __hip_bfloat16* Xb = (__hip_bfloat16*)(ws + (size_t)16 * 1024 * 1024);      // M*4096*2 = 64 MB

  // fused prep: 2048 (W1) + 2048 (W2) + M*IN/(8*256) (cvt) blocks
  const int cvt_blocks = (M * IN_DIM) / (8 * 256);
  prep_kernel<<<4096 + cvt_blocks, 256, 0, stream>>>(
      V, v2, V_R, v2_R, U, u1, v1, u2, U_R, u1_R, v1_R, u2_R, x, W1, W2, Xb);

  // GEMM1: (M/128) x (512/64) = 64 x 8 = 512 blocks, XCD-swizzled in-kernel
  gemm1_kernel<<<(M / 128) * (S2 / 64), 256, 0, stream>>>(Xb, W1, H);

  // GEMM2: (M/128) x (4096/128) = 64 x 32 = 2048 blocks
  gemm2_kernel<<<(M / 128) * (OUT_DIM / 128), 256, 0, stream>>>(H, W2, bias, out);
}